// Round 8
// baseline (389.159 us; speedup 1.0000x reference)
//
#include <hip/hip_runtime.h>

// Segmented exclusive product of (1 - alpha) over samples grouped by sorted
// ray_indices, plus visibility mask (trans >= 1e-4).
//
// Outputs (concatenated in d_out, fp32):
//   [0, n)      trans
//   [n, 2n)     vis (1.0f / 0.0f)
//
// Round 8 = round 7 with the compile fix: __builtin_nontemporal_store needs a
// native vector type, not HIP's float4 class -> use ext_vector_type(4).
//
// Single-pass FUSED kernel (decoupled look-back / chained scan).
//  - No seg_start table, no second pass over ray_indices: boundary flags come
//    from idx[i] != idx[i-1] locally per tile.
//  - Each block owns one 2048-sample tile (ticketed via atomicAdd so
//    predecessors are guaranteed started -> spin-safe regardless of dispatch
//    order). Publishes (trailing product, has_boundary) descriptor; incoming
//    prefix via look-back (expected depth 1: mean seg 128 << 2048).
//  - Cross-XCD safety: descriptor reads/writes via device-scope atomic RMW;
//    publish = agg atomicExch -> __threadfence -> flag atomicExch.
//  - Outputs via nontemporal vector stores (write-once; keep L2 for reads).
//  - fp64 scan retained: vis = (trans >= 1e-4) threshold bit must match the
//    np reference; fp64 is not the bottleneck.

#define EARLY_STOP_EPS 1e-4f
#define THREADS 256
#define EPL 8                       // elements per lane
#define TILE (THREADS * EPL)        // 2048 samples per block

typedef float fx4 __attribute__((ext_vector_type(4)));

struct Desc {
    unsigned flag;   // 0 = not ready; bit0 = ready; bit1 = has boundary
    unsigned pad;
    double   agg;    // product of (1-alpha) since last boundary in tile
};

__global__ __launch_bounds__(256) void init_kernel(
    unsigned* __restrict__ counter,
    Desc*     __restrict__ desc,
    int n_tiles)
{
    const int i = blockIdx.x * blockDim.x + threadIdx.x;
    if (i == 0) *counter = 0u;
    if (i < n_tiles) desc[i].flag = 0u;
}

__global__ __launch_bounds__(256) void fused_scan_kernel(
    const float* __restrict__ alphas,
    const int*   __restrict__ ray_indices,
    float*       __restrict__ out_trans,
    float*       __restrict__ out_vis,
    unsigned*    __restrict__ counter,
    Desc*        __restrict__ desc,
    int n_samples)
{
    __shared__ int      s_tile;
    __shared__ double   s_wagg[4];
    __shared__ unsigned s_wflag[4];
    __shared__ double   s_prefix;

    const int t    = threadIdx.x;
    const int lane = t & 63;
    const int wave = t >> 6;

    if (t == 0) s_tile = (int)atomicAdd(counter, 1u);
    __syncthreads();
    const int tile = s_tile;
    const int base = tile * TILE;
    const int i0   = base + t * EPL;

    // ---- loads: indices + alphas (32B-aligned fast path) ----
    int   c[EPL];
    float a[EPL];
    int   pidx;
    if (i0 + EPL - 1 < n_samples) {
        const int4 u0 = *reinterpret_cast<const int4*>(ray_indices + i0);
        const int4 u1 = *reinterpret_cast<const int4*>(ray_indices + i0 + 4);
        c[0]=u0.x; c[1]=u0.y; c[2]=u0.z; c[3]=u0.w;
        c[4]=u1.x; c[5]=u1.y; c[6]=u1.z; c[7]=u1.w;
        const float4 v0 = *reinterpret_cast<const float4*>(alphas + i0);
        const float4 v1 = *reinterpret_cast<const float4*>(alphas + i0 + 4);
        a[0]=v0.x; a[1]=v0.y; a[2]=v0.z; a[3]=v0.w;
        a[4]=v1.x; a[5]=v1.y; a[6]=v1.z; a[7]=v1.w;
        pidx = (i0 > 0) ? ray_indices[i0 - 1] : -1;
    } else if (i0 < n_samples) {
        int last = ray_indices[i0];
        #pragma unroll
        for (int e = 0; e < EPL; ++e) {
            const int idx = i0 + e;
            if (idx < n_samples) { c[e] = ray_indices[idx]; a[e] = alphas[idx]; last = c[e]; }
            else                 { c[e] = last; a[e] = 0.0f; }   // neutral
        }
        pidx = (i0 > 0) ? ray_indices[i0 - 1] : -1;
    } else {
        #pragma unroll
        for (int e = 0; e < EPL; ++e) { c[e] = 0; a[e] = 0.0f; }
        pidx = 0;  // c[0]==pidx -> no flag, x==1: fully neutral lane
    }

    // ---- factors, per-lane flags & segmented fold ----
    double   x[EPL];
    unsigned f[EPL];
    unsigned sm = 0;
    int prevc = pidx;
    #pragma unroll
    for (int e = 0; e < EPL; ++e) {
        f[e] = (c[e] != prevc) ? 1u : 0u;
        prevc = c[e];
        sm |= f[e] << e;
        x[e] = 1.0 - (double)a[e];
    }
    double p = x[0];
    #pragma unroll
    for (int e = 1; e < EPL; ++e) p = f[e] ? x[e] : p * x[e];

    // ---- wave-level segmented product scan (static flag mask) ----
    const unsigned long long fm  = __ballot(sm != 0u);
    const unsigned long long mle = (~0ull) >> (63 - lane);
    double sp = p;
    #pragma unroll
    for (int off = 1; off < 64; off <<= 1) {
        const double yp = __shfl_up(sp, off);
        const bool mult = (lane >= off) && ((fm & (mle ^ (mle >> off))) == 0ull);
        sp = mult ? sp * yp : sp;
    }
    double ep = __shfl_up(sp, 1);
    if (lane == 0) ep = 1.0;
    const bool ef = (fm & (mle >> 1)) != 0ull;   // boundary in lanes < lane

    // ---- publish wave aggregates to LDS ----
    if (lane == 63) { s_wagg[wave] = sp; s_wflag[wave] = (fm != 0ull) ? 1u : 0u; }
    __syncthreads();

    // ---- thread 0: block aggregate -> descriptor publish -> look-back ----
    if (t == 0) {
        double bagg = s_wagg[3];
        bool   bf   = s_wflag[3] != 0u;
        #pragma unroll
        for (int w = 2; w >= 0; --w) {
            if (!bf) { bagg *= s_wagg[w]; bf = s_wflag[w] != 0u; }
        }
        atomicExch((unsigned long long*)&desc[tile].agg, __double_as_longlong(bagg));
        __threadfence();
        atomicExch(&desc[tile].flag, 1u | (bf ? 2u : 0u));

        double pre = 1.0;
        for (int j = tile - 1; j >= 0; --j) {
            unsigned fl;
            while ((fl = atomicAdd(&desc[j].flag, 0u)) == 0u)
                __builtin_amdgcn_s_sleep(8);
            __threadfence();
            const double ag = __longlong_as_double(
                atomicAdd((unsigned long long*)&desc[j].agg, 0ull));
            pre *= ag;
            if (fl & 2u) break;
        }
        s_prefix = pre;
    }
    __syncthreads();

    // ---- per-wave incoming (waves < wave within block) ----
    double incw = 1.0;
    bool   blk  = false;
    #pragma unroll
    for (int w = 2; w >= 0; --w) {
        if (w < wave && !blk) { incw *= s_wagg[w]; blk = s_wflag[w] != 0u; }
    }
    const double e0 = ef ? ep : ep * incw * (blk ? 1.0 : s_prefix);

    // ---- per-element exclusive products -> fp32 ----
    float g[EPL];
    double tcur = f[0] ? 1.0 : e0;
    g[0] = (float)tcur;
    #pragma unroll
    for (int e = 1; e < EPL; ++e) {
        tcur = f[e] ? 1.0 : tcur * x[e - 1];
        g[e] = (float)tcur;
    }

    // ---- stores (nontemporal vector fast path) ----
    if (i0 + EPL - 1 < n_samples) {
        #pragma unroll
        for (int h = 0; h < 2; ++h) {
            fx4 tr, vi;
            tr.x = g[4*h+0]; tr.y = g[4*h+1]; tr.z = g[4*h+2]; tr.w = g[4*h+3];
            vi.x = (tr.x >= EARLY_STOP_EPS) ? 1.0f : 0.0f;
            vi.y = (tr.y >= EARLY_STOP_EPS) ? 1.0f : 0.0f;
            vi.z = (tr.z >= EARLY_STOP_EPS) ? 1.0f : 0.0f;
            vi.w = (tr.w >= EARLY_STOP_EPS) ? 1.0f : 0.0f;
            __builtin_nontemporal_store(tr, reinterpret_cast<fx4*>(out_trans + i0 + 4*h));
            __builtin_nontemporal_store(vi, reinterpret_cast<fx4*>(out_vis   + i0 + 4*h));
        }
    } else {
        #pragma unroll
        for (int e = 0; e < EPL; ++e) {
            const int idx = i0 + e;
            if (idx < n_samples) {
                out_trans[idx] = g[e];
                out_vis[idx]   = (g[e] >= EARLY_STOP_EPS) ? 1.0f : 0.0f;
            }
        }
    }
}

extern "C" void kernel_launch(void* const* d_in, const int* in_sizes, int n_in,
                              void* d_out, int out_size, void* d_ws, size_t ws_size,
                              hipStream_t stream) {
    const float* alphas      = (const float*)d_in[0];
    const int*   ray_indices = (const int*)d_in[1];
    const int n_samples = in_sizes[0];

    float* out_trans = (float*)d_out;
    float* out_vis   = out_trans + n_samples;

    unsigned* counter = (unsigned*)d_ws;
    Desc*     desc    = (Desc*)((char*)d_ws + 64);

    const int n_tiles = (n_samples + TILE - 1) / TILE;

    init_kernel<<<(n_tiles + THREADS - 1) / THREADS, THREADS, 0, stream>>>(
        counter, desc, n_tiles);

    fused_scan_kernel<<<n_tiles, THREADS, 0, stream>>>(
        alphas, ray_indices, out_trans, out_vis, counter, desc, n_samples);
}

// Round 9
// 25.975 us; speedup vs baseline: 14.9820x; 14.9820x over previous
//
#include <hip/hip_runtime.h>

// Segmented exclusive product of (1 - alpha) over samples grouped by sorted
// ray_indices, plus visibility mask (trans >= 1e-4).
//
// Outputs (concatenated in d_out, fp32):
//   [0, n)      trans
//   [n, 2n)     vis (1.0f / 0.0f)
//
// Round 9: single-pass, ZERO inter-block communication.
//  - r8's look-back protocol stalled the whole grid (389 us, VALUBusy 1.5%).
//    Traffic math shows fusion's only real win over two-pass is the kernel
//    boundary (~5 us), so no cross-block sync is justified.
//  - Each wave owns a FIXED 2048-sample span. Boundary flags derived locally
//    from idx[i] != idx[i-1] (the reference's exact `starts`).
//  - Incoming prefix across the span's left edge: bounded BACKWARD PROBE --
//    walk left in 64-wide wave-blocks, masked product-reduce of (1-alpha)
//    where idx == idx[S]; stop at the first block containing another ray.
//    Mean ~2 blocks (residual of a length-biased ~256 segment), data is the
//    left neighbor's primary stream -> L2 hits. No atomics, no workspace.
//  - Main loop: 512-elem chunks, per-lane 8-elem fold, static-flag-mask
//    segmented butterfly (structure verified in r4-r6), fp64 throughout
//    (vis >= 1e-4 threshold bit must match the np reference).
//  - Plain (not nontemporal) float4 stores: r8 showed NT doubled WRITE_SIZE.

#define EARLY_STOP_EPS 1e-4f
#define THREADS 256
#define EPL 8                        // elements per lane per chunk
#define CHUNK 512                    // 64 lanes * 8
#define SPAN 2048                    // per-wave span (4 chunks)

typedef float fx4 __attribute__((ext_vector_type(4)));

__global__ __launch_bounds__(256) void fused_span_kernel(
    const float* __restrict__ alphas,
    const int*   __restrict__ ray_indices,
    float*       __restrict__ out_trans,
    float*       __restrict__ out_vis,
    int n_samples)
{
    const int lane = threadIdx.x & 63;
    const int wave = threadIdx.x >> 6;
    const int wid  = blockIdx.x * (THREADS / 64) + wave;
    const int S    = wid * SPAN;
    if (S >= n_samples) return;
    const int E = min(S + SPAN, n_samples);

    // ---- incoming prefix (carry) via bounded backward probe ----
    double carry = 1.0;
    int chunk_prev = -1;                    // ray id of element S-1
    if (S > 0) {
        const int tgt  = ray_indices[S];     // uniform address -> broadcast
        const int prev = ray_indices[S - 1];
        chunk_prev = prev;
        if (prev == tgt) {                   // span starts mid-segment
            for (int be = S; be > 0; be -= 64) {
                const int  ii  = be - 64 + lane;
                const bool inb = (ii >= 0);
                const int  ci  = inb ? ray_indices[ii] : -1;
                const float ai = inb ? alphas[ii] : 0.0f;
                const bool  m  = (ci == tgt);   // contiguous run: exact mask
                double xv = m ? (1.0 - (double)ai) : 1.0;
                #pragma unroll
                for (int off = 1; off < 64; off <<= 1)
                    xv *= __shfl_xor(xv, off);   // all-reduce product
                carry *= xv;
                if (__ballot(ci != tgt) != 0ull) break;  // hit segment start
            }
        }
    }

    const unsigned long long mle = (~0ull) >> (63 - lane);  // bits <= lane

    for (int base = S; base < E; base += CHUNK) {
        const int i0 = base + lane * EPL;    // SPAN-aligned -> 32B-aligned

        // ---- loads (vector fast path; guarded tail on last span only) ----
        int   c[EPL];
        float a[EPL];
        if (i0 + EPL - 1 < E) {
            const int4 u0 = *reinterpret_cast<const int4*>(ray_indices + i0);
            const int4 u1 = *reinterpret_cast<const int4*>(ray_indices + i0 + 4);
            c[0]=u0.x; c[1]=u0.y; c[2]=u0.z; c[3]=u0.w;
            c[4]=u1.x; c[5]=u1.y; c[6]=u1.z; c[7]=u1.w;
            const float4 v0 = *reinterpret_cast<const float4*>(alphas + i0);
            const float4 v1 = *reinterpret_cast<const float4*>(alphas + i0 + 4);
            a[0]=v0.x; a[1]=v0.y; a[2]=v0.z; a[3]=v0.w;
            a[4]=v1.x; a[5]=v1.y; a[6]=v1.z; a[7]=v1.w;
        } else {
            int lastc = chunk_prev;          // neutral fill: f=0, x=1
            #pragma unroll
            for (int e = 0; e < EPL; ++e) {
                const int idx = i0 + e;
                if (idx < E) { c[e] = ray_indices[idx]; a[e] = alphas[idx]; lastc = c[e]; }
                else         { c[e] = lastc; a[e] = 0.0f; }
            }
            // lanes entirely beyond E: c[] = chunk_prev (uniform), f=0 below
        }

        // ---- flags from index discontinuities ----
        const int pl = __shfl_up(c[EPL - 1], 1);
        int prevc = (lane == 0) ? chunk_prev : pl;
        double   x[EPL];
        unsigned f[EPL];
        unsigned sm = 0;
        #pragma unroll
        for (int e = 0; e < EPL; ++e) {
            f[e] = (c[e] != prevc) ? 1u : 0u;
            prevc = c[e];
            sm |= f[e] << e;
            const bool valid = (i0 + e) < E;
            x[e] = valid ? (1.0 - (double)a[e]) : 1.0;
        }

        // ---- per-lane segmented fold ----
        double p = x[0];
        #pragma unroll
        for (int e = 1; e < EPL; ++e) p = f[e] ? x[e] : p * x[e];

        // ---- wave-level segmented product scan (static flag mask) ----
        const unsigned long long fm = __ballot(sm != 0u);
        double sp = p;
        #pragma unroll
        for (int off = 1; off < 64; off <<= 1) {
            const double yp = __shfl_up(sp, off);
            const bool mult = (lane >= off) &&
                              ((fm & (mle ^ (mle >> off))) == 0ull);
            sp = mult ? sp * yp : sp;
        }

        // ---- exclusive prefix entering this lane, with span carry ----
        double ep = __shfl_up(sp, 1);
        if (lane == 0) ep = 1.0;
        const bool ef = (fm & (mle >> 1)) != 0ull;  // boundary in lanes < lane
        const double e0 = ef ? ep : ep * carry;

        // ---- per-element exclusive products -> fp32 ----
        float g[EPL];
        double tcur = f[0] ? 1.0 : e0;
        g[0] = (float)tcur;
        #pragma unroll
        for (int e = 1; e < EPL; ++e) {
            tcur = f[e] ? 1.0 : tcur * x[e - 1];
            g[e] = (float)tcur;
        }

        // ---- stores (vector fast path) ----
        if (i0 + EPL - 1 < E) {
            #pragma unroll
            for (int h = 0; h < 2; ++h) {
                fx4 tr, vi;
                tr.x = g[4*h+0]; tr.y = g[4*h+1];
                tr.z = g[4*h+2]; tr.w = g[4*h+3];
                vi.x = (tr.x >= EARLY_STOP_EPS) ? 1.0f : 0.0f;
                vi.y = (tr.y >= EARLY_STOP_EPS) ? 1.0f : 0.0f;
                vi.z = (tr.z >= EARLY_STOP_EPS) ? 1.0f : 0.0f;
                vi.w = (tr.w >= EARLY_STOP_EPS) ? 1.0f : 0.0f;
                *reinterpret_cast<fx4*>(out_trans + i0 + 4*h) = tr;
                *reinterpret_cast<fx4*>(out_vis   + i0 + 4*h) = vi;
            }
        } else {
            #pragma unroll
            for (int e = 0; e < EPL; ++e) {
                const int idx = i0 + e;
                if (idx < E) {
                    out_trans[idx] = g[e];
                    out_vis[idx]   = (g[e] >= EARLY_STOP_EPS) ? 1.0f : 0.0f;
                }
            }
        }

        // ---- roll carry & prev-id into next chunk ----
        const double lp = __shfl(sp, 63);
        carry = (fm != 0ull) ? lp : carry * lp;
        chunk_prev = __shfl(c[EPL - 1], 63);
    }
}

extern "C" void kernel_launch(void* const* d_in, const int* in_sizes, int n_in,
                              void* d_out, int out_size, void* d_ws, size_t ws_size,
                              hipStream_t stream) {
    const float* alphas      = (const float*)d_in[0];
    const int*   ray_indices = (const int*)d_in[1];
    const int n_samples = in_sizes[0];

    float* out_trans = (float*)d_out;
    float* out_vis   = out_trans + n_samples;

    const int waves  = (n_samples + SPAN - 1) / SPAN;
    const int blocks = (waves + (THREADS / 64) - 1) / (THREADS / 64);

    fused_span_kernel<<<blocks, THREADS, 0, stream>>>(
        alphas, ray_indices, out_trans, out_vis, n_samples);
}